// Round 2
// baseline (15104.539 us; speedup 1.0000x reference)
//
#include <hip/hip_runtime.h>
#include <math.h>

// Problem constants (reference: B,T,D,H = 32,512,512,1024)
#define B_  32
#define T_  512
#define D_  512
#define H_  1024
#define FH  4096   // 4*H

// ---------------------------------------------------------------------------
// Adaptive workspace layout (bytes), chosen by ws_size at launch time:
//   wht  : [4096][1024] fp32 (transposed Wh)   = 16,777,216   @ ws+0
//   hb0  : [32][1024] fp32                     =    131,072   @ ws+16777216
//   hb1  : [32][1024] fp32                     =    131,072
//   cbuf : [32][1024] fp32                     =    131,072
//   xgc  : [Tc][B][4H] fp32 chunk buffer       = Tc*524288    @ ws+17170432
// Tc in {512, 64, 16, 4} -> totals {285.6 MB, 50.7 MB, 25.6 MB, 19.3 MB}
// ---------------------------------------------------------------------------

// ---- transpose Wh[1024][4096] -> WhT[4096][1024] --------------------------
__global__ void transpose_wh(const float* __restrict__ wh, float* __restrict__ wht) {
    __shared__ float tl[32][33];
    const int n0 = blockIdx.x * 32;   // gridDim.x = 128
    const int k0 = blockIdx.y * 32;   // gridDim.y = 32
    const int tx = threadIdx.x, ty = threadIdx.y;   // block (32,8)
#pragma unroll
    for (int j = 0; j < 4; ++j) {
        int r = ty + j * 8;
        tl[r][tx] = wh[(size_t)(k0 + r) * FH + n0 + tx];
    }
    __syncthreads();
#pragma unroll
    for (int j = 0; j < 4; ++j) {
        int r = ty + j * 8;
        wht[(size_t)(n0 + r) * H_ + k0 + tx] = tl[tx][r];
    }
}

// ---- fp32 GEMM + bias for a chunk of timesteps ----------------------------
// Computes xgc[r][n] = sum_k A[arow(r)][k] * W[k][n] + bias[n]
// for r in [0, Tc*32), arow(r) = (r&31)*512 + t0 + (r>>5)   (input row b*T+t)
// A row-major with row length K; W:[K,4096]; out xgc:[Tc*32][4096].
__global__ __launch_bounds__(256) void gemm_bias_chunk(
    const float* __restrict__ A, const float* __restrict__ W,
    const float* __restrict__ bias, float* __restrict__ out, int K, int t0) {
    __shared__ float As[16 * 132];
    __shared__ float Bs[16 * 132];
    const int t  = threadIdx.x;
    const int tn = t & 15, tm = t >> 4;
    const int n0 = blockIdx.x * 128;   // 32 n-tiles
    const int m0 = blockIdx.y * 128;   // Tc/4 m-tiles

    float acc[8][8];
#pragma unroll
    for (int i = 0; i < 8; ++i)
#pragma unroll
        for (int j = 0; j < 8; ++j) acc[i][j] = 0.f;

    for (int k0 = 0; k0 < K; k0 += 16) {
#pragma unroll
        for (int i = 0; i < 2; ++i) {   // A tile 128x16, store transposed As[k][m]
            int fid = t + i * 256;
            int m = fid >> 2, cc = fid & 3;
            int r = m0 + m;
            int arow = (r & 31) * 512 + t0 + (r >> 5);
            float4 av = *(const float4*)(A + (size_t)arow * K + k0 + cc * 4);
            As[(cc * 4 + 0) * 132 + m] = av.x;
            As[(cc * 4 + 1) * 132 + m] = av.y;
            As[(cc * 4 + 2) * 132 + m] = av.z;
            As[(cc * 4 + 3) * 132 + m] = av.w;
        }
#pragma unroll
        for (int i = 0; i < 2; ++i) {   // B tile 16x128, Bs[k][n]
            int fid = t + i * 256;
            int kk = fid >> 5, c = fid & 31;
            *(float4*)(Bs + kk * 132 + c * 4) =
                *(const float4*)(W + (size_t)(k0 + kk) * FH + n0 + c * 4);
        }
        __syncthreads();
#pragma unroll
        for (int kk = 0; kk < 16; ++kk) {
            float4 a0 = *(const float4*)(As + kk * 132 + tm * 8);
            float4 a1 = *(const float4*)(As + kk * 132 + tm * 8 + 4);
            float4 b0 = *(const float4*)(Bs + kk * 132 + tn * 4);        // n = 4tn..
            float4 b1 = *(const float4*)(Bs + kk * 132 + 64 + tn * 4);   // n = 64+4tn..
            float am[8] = {a0.x, a0.y, a0.z, a0.w, a1.x, a1.y, a1.z, a1.w};
            float bn[8] = {b0.x, b0.y, b0.z, b0.w, b1.x, b1.y, b1.z, b1.w};
#pragma unroll
            for (int mm = 0; mm < 8; ++mm)
#pragma unroll
                for (int nn = 0; nn < 8; ++nn) acc[mm][nn] += am[mm] * bn[nn];
        }
        __syncthreads();
    }

    float4 bb0 = *(const float4*)(bias + n0 + tn * 4);
    float4 bb1 = *(const float4*)(bias + n0 + 64 + tn * 4);
#pragma unroll
    for (int mm = 0; mm < 8; ++mm) {
        size_t orow = (size_t)(m0 + tm * 8 + mm);
        float4 v0, v1;
        v0.x = acc[mm][0] + bb0.x; v0.y = acc[mm][1] + bb0.y;
        v0.z = acc[mm][2] + bb0.z; v0.w = acc[mm][3] + bb0.w;
        v1.x = acc[mm][4] + bb1.x; v1.y = acc[mm][5] + bb1.y;
        v1.z = acc[mm][6] + bb1.z; v1.w = acc[mm][7] + bb1.w;
        *(float4*)(out + orow * FH + n0 + tn * 4)      = v0;
        *(float4*)(out + orow * FH + n0 + 64 + tn * 4) = v1;
    }
}

// ---- one LSTM time step ---------------------------------------------------
// Block owns 2 h-columns (hc0, hc0+1) -> 8 WhT rows {gt*1024 + hc0 + hcl}.
// 512 blocks x 256 threads. Lane map: gcg=t&1 (rows 0-3 / 4-7),
// sl=(t>>1)&31 (32 K-slices, k = ch*128 + sl*4), bg=t>>6 (= wave id; 8 batches).
__global__ __launch_bounds__(256) void lstm_step(
    const float* __restrict__ wht,    // [4096][1024]
    const float* __restrict__ xg_t,   // [B][4096] slab for this t
    const float* __restrict__ h_prev, // [32][1024]
    float* __restrict__ c,            // [32][1024] (in-place)
    float* __restrict__ h_next,       // [32][1024]
    float* __restrict__ y)            // d_out + t*H ; index [b*T*H + hc]
{
    __shared__ float smem[12448];     // 49.8 KB
    float* whs = smem;                // 8 rows * 1028 (stride pad) = 8224 floats
    float* hs  = smem + 8224;         // 32 * 132 = 4224 floats (one K-chunk of h)
    float* sc  = smem;                // overlay after compute: 8*32*33 = 8448
    float* g4  = smem + 8448;         // 4*64 gate buffer

    const int t   = threadIdx.x;
    const int hc0 = blockIdx.x * 2;

    // stage WhT rows for this block's 8 gate-columns (full K)
    float4* whs4 = (float4*)whs;
    const float4* wht4 = (const float4*)wht;
#pragma unroll
    for (int i = 0; i < 8; ++i) {
        int fid = t + i * 256;
        int r = fid >> 8, cc = fid & 255;
        int grow = (r >> 1) * H_ + hc0 + (r & 1);   // r = gt*2 + hcl
        whs4[r * 257 + cc] = wht4[(size_t)grow * 256 + cc];
    }

    const int gcg = t & 1;
    const int sl  = (t >> 1) & 31;
    const int bg  = t >> 6;

    float acc[4][8];
#pragma unroll
    for (int i = 0; i < 4; ++i)
#pragma unroll
        for (int j = 0; j < 8; ++j) acc[i][j] = 0.f;

    const float4* hp4 = (const float4*)h_prev;
    float4* hs4 = (float4*)hs;

    for (int ch = 0; ch < 8; ++ch) {      // K chunks of 128
#pragma unroll
        for (int i = 0; i < 4; ++i) {     // stage h[32][128]
            int fid = t + i * 256;
            int b = fid >> 5, cc = fid & 31;
            hs4[b * 33 + cc] = hp4[b * 256 + ch * 32 + cc];
        }
        __syncthreads();
        float4 w0 = whs4[(gcg * 4 + 0) * 257 + ch * 32 + sl];
        float4 w1 = whs4[(gcg * 4 + 1) * 257 + ch * 32 + sl];
        float4 w2 = whs4[(gcg * 4 + 2) * 257 + ch * 32 + sl];
        float4 w3 = whs4[(gcg * 4 + 3) * 257 + ch * 32 + sl];
#pragma unroll
        for (int bi = 0; bi < 8; ++bi) {
            float4 hv = hs4[(bg * 8 + bi) * 33 + sl];
            acc[0][bi] += w0.x * hv.x + w0.y * hv.y + w0.z * hv.z + w0.w * hv.w;
            acc[1][bi] += w1.x * hv.x + w1.y * hv.y + w1.z * hv.z + w1.w * hv.w;
            acc[2][bi] += w2.x * hv.x + w2.y * hv.y + w2.z * hv.z + w2.w * hv.w;
            acc[3][bi] += w3.x * hv.x + w3.y * hv.y + w3.z * hv.z + w3.w * hv.w;
        }
        __syncthreads();
    }

    // write per-slice partials (whs/hs dead now; sc overlays them)
#pragma unroll
    for (int gi = 0; gi < 4; ++gi)
#pragma unroll
        for (int bi = 0; bi < 8; ++bi)
            sc[((gcg * 4 + gi) * 32 + bg * 8 + bi) * 33 + sl] = acc[gi][bi];
    __syncthreads();

    // reduce 32 partials per output, add xg, stash gate in g4[gt][b*2+hcl]
    {
        int hcl = t & 1, b = (t >> 1) & 31, gt = t >> 6;
        int r = gt * 2 + hcl;
        float s = 0.f;
#pragma unroll
        for (int j = 0; j < 32; ++j) s += sc[(r * 32 + b) * 33 + j];
        s += xg_t[(size_t)b * FH + gt * H_ + hc0 + hcl];
        g4[gt * 64 + (t & 63)] = s;
    }
    __syncthreads();

    if (t < 64) {   // 2 hcols x 32 batches
        int hcl = t & 1, b = t >> 1;
        int hc = hc0 + hcl;
        float vi = g4[0 * 64 + t], vf = g4[1 * 64 + t];
        float vg = g4[2 * 64 + t], vo = g4[3 * 64 + t];
        float si = 1.f / (1.f + __expf(-vi));
        float sf = 1.f / (1.f + __expf(-vf));
        float so = 1.f / (1.f + __expf(-vo));
        float tg = tanhf(vg);
        size_t ci = (size_t)b * H_ + hc;
        float cn = sf * c[ci] + si * tg;
        c[ci] = cn;
        float hv = so * tanhf(cn);
        h_next[ci] = hv;
        y[(size_t)b * T_ * H_ + hc] = hv;
    }
}

// ---------------------------------------------------------------------------
extern "C" void kernel_launch(void* const* d_in, const int* in_sizes, int n_in,
                              void* d_out, int out_size, void* d_ws, size_t ws_size,
                              hipStream_t stream) {
    (void)in_sizes; (void)n_in; (void)out_size;
    const float* x   = (const float*)d_in[0];
    const float* Wx0 = (const float*)d_in[1];
    const float* Wh0 = (const float*)d_in[2];
    const float* b0  = (const float*)d_in[3];
    const float* Wx1 = (const float*)d_in[4];
    const float* Wh1 = (const float*)d_in[5];
    const float* b1  = (const float*)d_in[6];
    float* out = (float*)d_out;

    char* ws = (char*)d_ws;
    float* wht  = (float*)(ws);                      // 16,777,216 B
    float* hb0  = (float*)(ws + 16777216ull);        //    131,072 B
    float* hb1  = hb0 + 32 * 1024;
    float* cbuf = hb1 + 32 * 1024;
    float* xgc  = (float*)(ws + 17170432ull);        // Tc * 524,288 B

    // Pick the largest chunk size the workspace can hold (ws_size is constant
    // across calls, so this branch is identical every call -> graph-safe).
    const size_t base = 17170432ull;
    int Tc;
    if      (ws_size >= base + 512ull * 524288ull) Tc = 512;  // 285.6 MB
    else if (ws_size >= base +  64ull * 524288ull) Tc = 64;   //  50.7 MB
    else if (ws_size >= base +  16ull * 524288ull) Tc = 16;   //  25.6 MB
    else                                           Tc = 4;    //  19.3 MB

    for (int layer = 0; layer < 2; ++layer) {
        const float* Aptr = layer ? out : x;
        const float* Wxp  = layer ? Wx1 : Wx0;
        const float* Whp  = layer ? Wh1 : Wh0;
        const float* bp   = layer ? b1  : b0;
        const int    K    = layer ? H_  : D_;

        transpose_wh<<<dim3(128, 32), dim3(32, 8), 0, stream>>>(Whp, wht);
        hipMemsetAsync(hb0, 0, 131072, stream);
        hipMemsetAsync(cbuf, 0, 131072, stream);

        for (int t0 = 0; t0 < T_; t0 += Tc) {
            // Project x (or y0) for timesteps [t0, t0+Tc). For layer 1 this
            // reads out[] rows t in-chunk only, which later step launches
            // have not yet overwritten -> ordering-safe.
            gemm_bias_chunk<<<dim3(32, Tc / 4), 256, 0, stream>>>(
                Aptr, Wxp, bp, xgc, K, t0);
            for (int tt = t0; tt < t0 + Tc; ++tt) {
                const float* hp = (tt & 1) ? hb1 : hb0;
                float* hn       = (tt & 1) ? hb0 : hb1;
                lstm_step<<<512, 256, 0, stream>>>(
                    wht, xgc + (size_t)(tt - t0) * B_ * FH,
                    hp, cbuf, hn, out + (size_t)tt * H_);
            }
        }
    }
}